// Round 1
// baseline (83.155 us; speedup 1.0000x reference)
//
#include <hip/hip_runtime.h>
#include <hip/hip_bf16.h>
#include <hip/hip_fp16.h>

#define B_ 4
#define N_ 1024
#define C_ 512
#define H_ 8
#define CH_ 64
// tokens = B_*N_ = 4096

typedef _Float16 f16x8 __attribute__((ext_vector_type(8)));
typedef _Float16 f16x4 __attribute__((ext_vector_type(4)));
typedef float f32x4 __attribute__((ext_vector_type(4)));

// ---------------- Kernel 1: convert q_x / kv_x f32 -> f16 ----------------
__global__ void cvt_f32_f16(const float* __restrict__ xq, const float* __restrict__ xkv,
                            _Float16* __restrict__ oq, _Float16* __restrict__ okv) {
  const int n4 = (B_ * N_ * C_) / 4;  // float4 count per tensor
  int stride = gridDim.x * blockDim.x;
  for (int idx = blockIdx.x * blockDim.x + threadIdx.x; idx < 2 * n4; idx += stride) {
    const float4* src = (idx < n4) ? (const float4*)xq : (const float4*)xkv;
    _Float16* dst = (idx < n4) ? oq : okv;
    int j = (idx < n4) ? idx : idx - n4;
    float4 v = src[j];
    f16x4 h;
    h[0] = (_Float16)v.x; h[1] = (_Float16)v.y;
    h[2] = (_Float16)v.z; h[3] = (_Float16)v.w;
    *(f16x4*)(dst + (size_t)j * 4) = h;
  }
}

// ---------------- Kernel 2: W [k][n] f32 -> WT [n][k] f16 (5 weights) ----------------
__global__ void transpose_w(const float* __restrict__ Wq, const float* __restrict__ Wk,
                            const float* __restrict__ Wv, const float* __restrict__ Wg,
                            const float* __restrict__ Wo, _Float16* __restrict__ WT) {
  int s = blockIdx.z;
  const float* W = (s == 0) ? Wq : (s == 1) ? Wk : (s == 2) ? Wv : (s == 3) ? Wg : Wo;
  __shared__ float tile[32][33];
  int tx = threadIdx.x & 31, ty = threadIdx.x >> 5;  // 32 x 8
  int k0 = blockIdx.x * 32, n0 = blockIdx.y * 32;
  #pragma unroll
  for (int r = 0; r < 32; r += 8)
    tile[ty + r][tx] = W[(size_t)(k0 + ty + r) * C_ + n0 + tx];
  __syncthreads();
  _Float16* dst = WT + (size_t)s * C_ * C_;
  #pragma unroll
  for (int r = 0; r < 32; r += 8)
    dst[(size_t)(n0 + ty + r) * C_ + k0 + tx] = (_Float16)tile[tx][ty + r];
}

// ---------------- Kernel 3: fused projection GEMM ----------------
// virtual C [4096 x 2048]: cols 0-511 Q(q_x), 512-1023 K(kv_x), 1024-1535 V(kv_x), 1536-2047 G(q_x)
__global__ __launch_bounds__(256, 2) void proj_gemm(
    const _Float16* __restrict__ xq16, const _Float16* __restrict__ xkv16,
    const _Float16* __restrict__ WT, const float* __restrict__ bg,
    _Float16* __restrict__ Qb, _Float16* __restrict__ Kb,
    _Float16* __restrict__ Vt, float* __restrict__ Gb) {
  int nt0 = blockIdx.x * 128;
  int m0 = blockIdx.y * 128;
  int sel = nt0 >> 9;        // 0:Q 1:K 2:V 3:G
  int n0 = nt0 & 511;
  const _Float16* X = (sel == 0 || sel == 3) ? xq16 : xkv16;
  const _Float16* Wt = WT + (size_t)sel * C_ * C_;

  __shared__ __align__(16) char lds[32768];
  char* ldsA = lds;
  char* ldsB = lds + 16384;

  int tid = threadIdx.x;
  int lane = tid & 63, w = tid >> 6;
  int wr = w >> 1, wc = w & 1;
  int lr = lane & 15, lg = lane >> 4;

  f32x4 acc[4][4];
  #pragma unroll
  for (int i = 0; i < 4; i++)
    #pragma unroll
    for (int j = 0; j < 4; j++)
      #pragma unroll
      for (int r = 0; r < 4; r++) acc[i][j][r] = 0.f;

  int srow = tid >> 3, scol = tid & 7;

  for (int k0 = 0; k0 < C_; k0 += 64) {
    __syncthreads();
    #pragma unroll
    for (int p = 0; p < 4; p++) {
      int r = p * 32 + srow;
      *(f16x8*)(ldsA + ((r * 128 + scol * 16) ^ ((r & 7) << 4))) =
          *(const f16x8*)(X + (size_t)(m0 + r) * C_ + k0 + scol * 8);
      *(f16x8*)(ldsB + ((r * 128 + scol * 16) ^ ((r & 7) << 4))) =
          *(const f16x8*)(Wt + (size_t)(n0 + r) * C_ + k0 + scol * 8);
    }
    __syncthreads();
    #pragma unroll
    for (int kh = 0; kh < 2; kh++) {
      f16x8 a[4], b[4];
      #pragma unroll
      for (int i = 0; i < 4; i++) {
        int row = wr * 64 + i * 16 + lr;
        a[i] = *(const f16x8*)(ldsA + ((row * 128 + kh * 64 + lg * 16) ^ ((row & 7) << 4)));
        int col = wc * 64 + i * 16 + lr;
        b[i] = *(const f16x8*)(ldsB + ((col * 128 + kh * 64 + lg * 16) ^ ((col & 7) << 4)));
      }
      #pragma unroll
      for (int i = 0; i < 4; i++)
        #pragma unroll
        for (int j = 0; j < 4; j++)
          acc[i][j] = __builtin_amdgcn_mfma_f32_16x16x32_f16(a[i], b[j], acc[i][j], 0, 0, 0);
    }
  }

  const float inv_sqrt = 0.125f;  // 1/sqrt(64)
  #pragma unroll
  for (int i = 0; i < 4; i++) {
    int token = m0 + wr * 64 + i * 16 + lg * 4;
    #pragma unroll
    for (int j = 0; j < 4; j++) {
      int col = n0 + wc * 64 + j * 16 + lr;
      f32x4 v = acc[i][j];
      if (sel == 0) {
        #pragma unroll
        for (int r = 0; r < 4; r++)
          Qb[(size_t)(token + r) * C_ + col] = (_Float16)(v[r] * inv_sqrt);
      } else if (sel == 1) {
        #pragma unroll
        for (int r = 0; r < 4; r++)
          Kb[(size_t)(token + r) * C_ + col] = (_Float16)v[r];
      } else if (sel == 2) {
        int bb = token >> 10;
        int nn = token & 1023;
        int hh = col >> 6, ch = col & 63;
        f16x4 pk;
        #pragma unroll
        for (int r = 0; r < 4; r++) pk[r] = (_Float16)v[r];
        *(f16x4*)(Vt + (size_t)((bb * H_ + hh) * CH_ + ch) * N_ + nn) = pk;
      } else {
        #pragma unroll
        for (int r = 0; r < 4; r++) {
          float x = v[r] + bg[col];
          Gb[(size_t)(token + r) * C_ + col] = 1.f / (1.f + __expf(-x));
        }
      }
    }
  }
}

// ---------------- Kernel 4: flash attention per (b, h, 64-row q-tile) ----------------
__global__ __launch_bounds__(256, 2) void attn(
    const _Float16* __restrict__ Qb, const _Float16* __restrict__ Kb,
    const _Float16* __restrict__ Vt, const float* __restrict__ Gb,
    const float* __restrict__ bias_mask, const float* __restrict__ bias_pair,
    _Float16* __restrict__ Ob) {
  int bid = blockIdx.x;
  int b = bid & 3, h = (bid >> 2) & 7, qt = bid >> 5;  // b fastest: same-h blocks share bias_pair in L2
  int q0 = qt * 64;
  int tid = threadIdx.x, lane = tid & 63, w = tid >> 6;
  int lr = lane & 15, lg = lane >> 4;

  __shared__ __align__(16) char lds[49152];
  char* ldsK = lds;            // [128][64] f16, 16KB
  char* ldsV = lds + 16384;    // [64][128] f16 (V^T), 16KB
  char* ldsP = lds + 32768;    // per-wave [16][128] f16, 4KB each

  // Q fragments in registers: wave w owns q rows q0+16w .. q0+16w+15
  f16x8 qf[2];
  {
    int token = b * N_ + q0 + w * 16 + lr;
    const _Float16* qp = Qb + (size_t)token * C_ + h * CH_;
    qf[0] = *(const f16x8*)(qp + lg * 8);
    qf[1] = *(const f16x8*)(qp + 32 + lg * 8);
  }

  f32x4 acc_o[4];
  #pragma unroll
  for (int j = 0; j < 4; j++)
    #pragma unroll
    for (int r = 0; r < 4; r++) acc_o[j][r] = 0.f;
  float m_run[4], l_run[4];
  #pragma unroll
  for (int r = 0; r < 4; r++) { m_run[r] = -1e30f; l_run[r] = 0.f; }

  int srow = tid >> 3, scol = tid & 7;    // K staging
  int vrow = tid >> 4, vcol = tid & 15;   // V^T staging

  for (int kt = 0; kt < 8; kt++) {
    __syncthreads();
    #pragma unroll
    for (int p = 0; p < 4; p++) {
      int r = p * 32 + srow;
      *(f16x8*)(ldsK + ((r * 128 + scol * 16) ^ ((r & 7) << 4))) =
          *(const f16x8*)(Kb + (size_t)(b * N_ + kt * 128 + r) * C_ + h * CH_ + scol * 8);
    }
    #pragma unroll
    for (int p = 0; p < 4; p++) {
      int r = p * 16 + vrow;
      *(f16x8*)(ldsV + ((r * 256 + vcol * 16) ^ ((r & 7) << 4))) =
          *(const f16x8*)(Vt + (size_t)((b * H_ + h) * CH_ + r) * N_ + kt * 128 + vcol * 8);
    }
    __syncthreads();

    // S = Q K^T : rows 16w..16w+15, cols kt*128..+127
    f32x4 s[8];
    #pragma unroll
    for (int ct = 0; ct < 8; ct++) {
      #pragma unroll
      for (int r = 0; r < 4; r++) s[ct][r] = 0.f;
      #pragma unroll
      for (int kh = 0; kh < 2; kh++) {
        int row = ct * 16 + lr;
        f16x8 kf = *(const f16x8*)(ldsK + ((row * 128 + kh * 64 + lg * 16) ^ ((row & 7) << 4)));
        s[ct] = __builtin_amdgcn_mfma_f32_16x16x32_f16(qf[kh], kf, s[ct], 0, 0, 0);
      }
    }
    // additive biases (f32)
    int qrow = q0 + w * 16 + lg * 4;
    #pragma unroll
    for (int ct = 0; ct < 8; ct++) {
      float bm = bias_mask[b * N_ + kt * 128 + ct * 16 + lr];
      const float* bp = bias_pair + ((size_t)h * N_ + qrow) * N_ + kt * 128 + ct * 16 + lr;
      #pragma unroll
      for (int r = 0; r < 4; r++) s[ct][r] += bm + bp[(size_t)r * N_];
    }
    // online softmax per row (row = 4*lg + r within wave tile)
    #pragma unroll
    for (int r = 0; r < 4; r++) {
      float mx = s[0][r];
      #pragma unroll
      for (int ct = 1; ct < 8; ct++) mx = fmaxf(mx, s[ct][r]);
      #pragma unroll
      for (int o = 1; o < 16; o <<= 1) mx = fmaxf(mx, __shfl_xor(mx, o, 64));
      float m_new = fmaxf(m_run[r], mx);
      float sc = __expf(m_run[r] - m_new);
      m_run[r] = m_new;
      float sum = 0.f;
      #pragma unroll
      for (int ct = 0; ct < 8; ct++) {
        float p = __expf(s[ct][r] - m_new);
        s[ct][r] = p;
        sum += p;
      }
      #pragma unroll
      for (int o = 1; o < 16; o <<= 1) sum += __shfl_xor(sum, o, 64);
      l_run[r] = l_run[r] * sc + sum;
      #pragma unroll
      for (int j = 0; j < 4; j++) acc_o[j][r] *= sc;
    }
    // P -> per-wave LDS (f16), layout change for PV A-fragments
    char* myP = ldsP + w * 4096;
    #pragma unroll
    for (int ct = 0; ct < 8; ct++) {
      #pragma unroll
      for (int r = 0; r < 4; r++) {
        int row = lg * 4 + r;
        *(_Float16*)(myP + ((row * 256 + (ct * 16 + lr) * 2) ^ ((row & 7) << 4))) =
            (_Float16)s[ct][r];
      }
    }
    // O += P V  (V^T staged as [ch][kk])
    #pragma unroll
    for (int ks = 0; ks < 4; ks++) {
      f16x8 pf = *(const f16x8*)(myP + ((lr * 256 + ks * 64 + lg * 16) ^ ((lr & 7) << 4)));
      #pragma unroll
      for (int cc = 0; cc < 4; cc++) {
        int vr = cc * 16 + lr;
        f16x8 vf = *(const f16x8*)(ldsV + ((vr * 256 + ks * 64 + lg * 16) ^ ((vr & 7) << 4)));
        acc_o[cc] = __builtin_amdgcn_mfma_f32_16x16x32_f16(pf, vf, acc_o[cc], 0, 0, 0);
      }
    }
  }

  // epilogue: 1/l, gate with G, store f16
  #pragma unroll
  for (int cc = 0; cc < 4; cc++) {
    #pragma unroll
    for (int r = 0; r < 4; r++) {
      int token = b * N_ + q0 + w * 16 + lg * 4 + r;
      int col = h * CH_ + cc * 16 + lr;
      float o = acc_o[cc][r] / l_run[r];
      float gv = Gb[(size_t)token * C_ + col];
      Ob[(size_t)token * C_ + col] = (_Float16)(o * gv);
    }
  }
}

// ---------------- Kernel 5: output GEMM + bo ----------------
__global__ __launch_bounds__(256, 2) void out_gemm(
    const _Float16* __restrict__ Ob, const _Float16* __restrict__ WTo,
    const float* __restrict__ bo, float* __restrict__ out) {
  int n0 = blockIdx.x * 128;
  int m0 = blockIdx.y * 128;
  __shared__ __align__(16) char lds[32768];
  char* ldsA = lds;
  char* ldsB = lds + 16384;
  int tid = threadIdx.x;
  int lane = tid & 63, w = tid >> 6;
  int wr = w >> 1, wc = w & 1;
  int lr = lane & 15, lg = lane >> 4;
  f32x4 acc[4][4];
  #pragma unroll
  for (int i = 0; i < 4; i++)
    #pragma unroll
    for (int j = 0; j < 4; j++)
      #pragma unroll
      for (int r = 0; r < 4; r++) acc[i][j][r] = 0.f;
  int srow = tid >> 3, scol = tid & 7;
  for (int k0 = 0; k0 < C_; k0 += 64) {
    __syncthreads();
    #pragma unroll
    for (int p = 0; p < 4; p++) {
      int r = p * 32 + srow;
      *(f16x8*)(ldsA + ((r * 128 + scol * 16) ^ ((r & 7) << 4))) =
          *(const f16x8*)(Ob + (size_t)(m0 + r) * C_ + k0 + scol * 8);
      *(f16x8*)(ldsB + ((r * 128 + scol * 16) ^ ((r & 7) << 4))) =
          *(const f16x8*)(WTo + (size_t)(n0 + r) * C_ + k0 + scol * 8);
    }
    __syncthreads();
    #pragma unroll
    for (int kh = 0; kh < 2; kh++) {
      f16x8 a[4], bfr[4];
      #pragma unroll
      for (int i = 0; i < 4; i++) {
        int row = wr * 64 + i * 16 + lr;
        a[i] = *(const f16x8*)(ldsA + ((row * 128 + kh * 64 + lg * 16) ^ ((row & 7) << 4)));
        int col = wc * 64 + i * 16 + lr;
        bfr[i] = *(const f16x8*)(ldsB + ((col * 128 + kh * 64 + lg * 16) ^ ((col & 7) << 4)));
      }
      #pragma unroll
      for (int i = 0; i < 4; i++)
        #pragma unroll
        for (int j = 0; j < 4; j++)
          acc[i][j] = __builtin_amdgcn_mfma_f32_16x16x32_f16(a[i], bfr[j], acc[i][j], 0, 0, 0);
    }
  }
  #pragma unroll
  for (int i = 0; i < 4; i++) {
    int token = m0 + wr * 64 + i * 16 + lg * 4;
    #pragma unroll
    for (int j = 0; j < 4; j++) {
      int col = n0 + wc * 64 + j * 16 + lr;
      float bb = bo[col];
      #pragma unroll
      for (int r = 0; r < 4; r++)
        out[(size_t)(token + r) * C_ + col] = acc[i][j][r] + bb;
    }
  }
}

extern "C" void kernel_launch(void* const* d_in, const int* in_sizes, int n_in,
                              void* d_out, int out_size, void* d_ws, size_t ws_size,
                              hipStream_t stream) {
  const float* q_x = (const float*)d_in[0];
  const float* kv_x = (const float*)d_in[1];
  const float* bias_mask = (const float*)d_in[2];
  const float* bias_pair = (const float*)d_in[3];
  const float* Wq = (const float*)d_in[4];
  const float* Wk = (const float*)d_in[5];
  const float* Wv = (const float*)d_in[6];
  const float* Wg = (const float*)d_in[7];
  const float* bg = (const float*)d_in[8];
  const float* Wo = (const float*)d_in[9];
  const float* bo = (const float*)d_in[10];
  float* out = (float*)d_out;

  char* ws = (char*)d_ws;
  const size_t MB = 1024 * 1024;
  _Float16* xq16 = (_Float16*)(ws + 0);        // 4 MB
  _Float16* xkv16 = (_Float16*)(ws + 4 * MB);  // 4 MB
  _Float16* WT = (_Float16*)(ws + 8 * MB);     // 2.5 MB (5 x 512 x 512 f16)
  _Float16* Qb = (_Float16*)(ws + 11 * MB);    // 4 MB
  _Float16* Kb = (_Float16*)(ws + 15 * MB);    // 4 MB
  _Float16* Vt = (_Float16*)(ws + 19 * MB);    // 4 MB
  float* Gb = (float*)(ws + 23 * MB);          // 8 MB
  _Float16* Ob = (_Float16*)(ws + 31 * MB);    // 4 MB

  cvt_f32_f16<<<2048, 256, 0, stream>>>(q_x, kv_x, xq16, xkv16);
  transpose_w<<<dim3(16, 16, 5), 256, 0, stream>>>(Wq, Wk, Wv, Wg, Wo, WT);
  proj_gemm<<<dim3(16, 32), 256, 0, stream>>>(xq16, xkv16, WT, bg, Qb, Kb, Vt, Gb);
  attn<<<512, 256, 0, stream>>>(Qb, Kb, Vt, Gb, bias_mask, bias_pair, Ob);
  out_gemm<<<dim3(4, 32), 256, 0, stream>>>(Ob, WT + 4 * (size_t)C_ * C_, bo, out);
}

// Round 2
// 77.207 us; speedup vs baseline: 1.0770x; 1.0770x over previous
//
#include <hip/hip_runtime.h>
#include <hip/hip_bf16.h>
#include <hip/hip_fp16.h>

#define B_ 4
#define N_ 1024
#define C_ 512
#define H_ 8
#define CH_ 64
// tokens = B_*N_ = 4096

typedef _Float16 f16x8 __attribute__((ext_vector_type(8)));
typedef _Float16 f16x4 __attribute__((ext_vector_type(4)));
typedef float f32x4 __attribute__((ext_vector_type(4)));

// ---------------- Kernel 1: convert q_x / kv_x f32 -> f16 ----------------
__global__ void cvt_f32_f16(const float* __restrict__ xq, const float* __restrict__ xkv,
                            _Float16* __restrict__ oq, _Float16* __restrict__ okv) {
  const int n4 = (B_ * N_ * C_) / 4;  // float4 count per tensor
  int stride = gridDim.x * blockDim.x;
  for (int idx = blockIdx.x * blockDim.x + threadIdx.x; idx < 2 * n4; idx += stride) {
    const float4* src = (idx < n4) ? (const float4*)xq : (const float4*)xkv;
    _Float16* dst = (idx < n4) ? oq : okv;
    int j = (idx < n4) ? idx : idx - n4;
    float4 v = src[j];
    f16x4 h;
    h[0] = (_Float16)v.x; h[1] = (_Float16)v.y;
    h[2] = (_Float16)v.z; h[3] = (_Float16)v.w;
    *(f16x4*)(dst + (size_t)j * 4) = h;
  }
}

// ---------------- Kernel 2: W [k][n] f32 -> WT [n][k] f16 (5 weights) ----------------
__global__ void transpose_w(const float* __restrict__ Wq, const float* __restrict__ Wk,
                            const float* __restrict__ Wv, const float* __restrict__ Wg,
                            const float* __restrict__ Wo, _Float16* __restrict__ WT) {
  int s = blockIdx.z;
  const float* W = (s == 0) ? Wq : (s == 1) ? Wk : (s == 2) ? Wv : (s == 3) ? Wg : Wo;
  __shared__ float tile[32][33];
  int tx = threadIdx.x & 31, ty = threadIdx.x >> 5;  // 32 x 8
  int k0 = blockIdx.x * 32, n0 = blockIdx.y * 32;
  #pragma unroll
  for (int r = 0; r < 32; r += 8)
    tile[ty + r][tx] = W[(size_t)(k0 + ty + r) * C_ + n0 + tx];
  __syncthreads();
  _Float16* dst = WT + (size_t)s * C_ * C_;
  #pragma unroll
  for (int r = 0; r < 32; r += 8)
    dst[(size_t)(n0 + ty + r) * C_ + k0 + tx] = (_Float16)tile[tx][ty + r];
}

// ---------------- Kernel 3: fused projection GEMM ----------------
// virtual C [4096 x 2048]: cols 0-511 Q(q_x), 512-1023 K(kv_x), 1024-1535 V(kv_x), 1536-2047 G(q_x)
__global__ __launch_bounds__(256, 2) void proj_gemm(
    const _Float16* __restrict__ xq16, const _Float16* __restrict__ xkv16,
    const _Float16* __restrict__ WT, const float* __restrict__ bg,
    _Float16* __restrict__ Qb, _Float16* __restrict__ Kb,
    _Float16* __restrict__ Vt, _Float16* __restrict__ Gb) {
  int nt0 = blockIdx.x * 128;
  int m0 = blockIdx.y * 128;
  int sel = nt0 >> 9;        // 0:Q 1:K 2:V 3:G
  int n0 = nt0 & 511;
  const _Float16* X = (sel == 0 || sel == 3) ? xq16 : xkv16;
  const _Float16* Wt = WT + (size_t)sel * C_ * C_;

  __shared__ __align__(16) char lds[32768];
  char* ldsA = lds;
  char* ldsB = lds + 16384;

  int tid = threadIdx.x;
  int lane = tid & 63, w = tid >> 6;
  int wr = w >> 1, wc = w & 1;
  int lr = lane & 15, lg = lane >> 4;

  f32x4 acc[4][4];
  #pragma unroll
  for (int i = 0; i < 4; i++)
    #pragma unroll
    for (int j = 0; j < 4; j++)
      #pragma unroll
      for (int r = 0; r < 4; r++) acc[i][j][r] = 0.f;

  int srow = tid >> 3, scol = tid & 7;

  for (int k0 = 0; k0 < C_; k0 += 64) {
    __syncthreads();
    #pragma unroll
    for (int p = 0; p < 4; p++) {
      int r = p * 32 + srow;
      *(f16x8*)(ldsA + ((r * 128 + scol * 16) ^ ((r & 7) << 4))) =
          *(const f16x8*)(X + (size_t)(m0 + r) * C_ + k0 + scol * 8);
      *(f16x8*)(ldsB + ((r * 128 + scol * 16) ^ ((r & 7) << 4))) =
          *(const f16x8*)(Wt + (size_t)(n0 + r) * C_ + k0 + scol * 8);
    }
    __syncthreads();
    #pragma unroll
    for (int kh = 0; kh < 2; kh++) {
      f16x8 a[4], b[4];
      #pragma unroll
      for (int i = 0; i < 4; i++) {
        int row = wr * 64 + i * 16 + lr;
        a[i] = *(const f16x8*)(ldsA + ((row * 128 + kh * 64 + lg * 16) ^ ((row & 7) << 4)));
        int col = wc * 64 + i * 16 + lr;
        b[i] = *(const f16x8*)(ldsB + ((col * 128 + kh * 64 + lg * 16) ^ ((col & 7) << 4)));
      }
      #pragma unroll
      for (int i = 0; i < 4; i++)
        #pragma unroll
        for (int j = 0; j < 4; j++)
          acc[i][j] = __builtin_amdgcn_mfma_f32_16x16x32_f16(a[i], b[j], acc[i][j], 0, 0, 0);
    }
  }

  const float inv_sqrt = 0.125f;  // 1/sqrt(64)
  #pragma unroll
  for (int i = 0; i < 4; i++) {
    int token = m0 + wr * 64 + i * 16 + lg * 4;
    #pragma unroll
    for (int j = 0; j < 4; j++) {
      int col = n0 + wc * 64 + j * 16 + lr;
      f32x4 v = acc[i][j];
      if (sel == 0) {
        #pragma unroll
        for (int r = 0; r < 4; r++)
          Qb[(size_t)(token + r) * C_ + col] = (_Float16)(v[r] * inv_sqrt);
      } else if (sel == 1) {
        #pragma unroll
        for (int r = 0; r < 4; r++)
          Kb[(size_t)(token + r) * C_ + col] = (_Float16)v[r];
      } else if (sel == 2) {
        int bb = token >> 10;
        int nn = token & 1023;
        int hh = col >> 6, ch = col & 63;
        f16x4 pk;
        #pragma unroll
        for (int r = 0; r < 4; r++) pk[r] = (_Float16)v[r];
        *(f16x4*)(Vt + (size_t)((bb * H_ + hh) * CH_ + ch) * N_ + nn) = pk;
      } else {
        #pragma unroll
        for (int r = 0; r < 4; r++) {
          float x = v[r] + bg[col];
          Gb[(size_t)(token + r) * C_ + col] = (_Float16)(1.f / (1.f + __expf(-x)));
        }
      }
    }
  }
}

// ---------------- Kernel 4: flash attention, S^T formulation ----------------
// grid 512: h = bid&7 (one head per XCD under round-robin), b = (bid>>3)&3, qt = bid>>5
// Wave w owns q rows q0+16w..+15. All MFMAs transposed: S^T = K Q^T, O^T = V^T P^T.
// Lane mapping of every C/D tile: col = q = lr, rows = (k or ch) = 16t + lg*4 + r
//  -> bias_pair/bias_mask are float4 loads, P-write is f16x4, m/l are per-lane scalars.
__global__ __launch_bounds__(256, 2) void attn(
    const _Float16* __restrict__ Qb, const _Float16* __restrict__ Kb,
    const _Float16* __restrict__ Vt, const _Float16* __restrict__ Gb,
    const float* __restrict__ bias_mask, const float* __restrict__ bias_pair,
    _Float16* __restrict__ Ob) {
  int bid = blockIdx.x;
  int h = bid & 7, b = (bid >> 3) & 3, qt = bid >> 5;
  int q0 = qt * 64;
  int tid = threadIdx.x, lane = tid & 63, w = tid >> 6;
  int lr = lane & 15, lg = lane >> 4;

  __shared__ __align__(16) char lds[49152];
  char* ldsK = lds;            // [128 k][64 c] f16, 16KB
  char* ldsV = lds + 16384;    // [64 ch][128 k] f16 (V^T), 16KB
  char* ldsP = lds + 32768;    // per-wave [16 q][128 k] f16, 4KB each

  // Q fragments (B-operand): lane: q row = lr, c = kh*32 + lg*8..
  f16x8 qf[2];
  {
    int token = b * N_ + q0 + w * 16 + lr;
    const _Float16* qp = Qb + (size_t)token * C_ + h * CH_;
    qf[0] = *(const f16x8*)(qp + lg * 8);
    qf[1] = *(const f16x8*)(qp + 32 + lg * 8);
  }

  f32x4 acc_o[4];  // O^T: rows ch = cc*16+lg*4+r, col q = lr
  #pragma unroll
  for (int j = 0; j < 4; j++)
    #pragma unroll
    for (int r = 0; r < 4; r++) acc_o[j][r] = 0.f;
  float m_run = -1e30f, l_run = 0.f;  // per-lane scalars (q = lr)

  int srow = tid >> 3, scol = tid & 7;    // K staging: 32 rows x 8x8 f16
  int vrow = tid >> 4, vcol = tid & 15;   // V^T staging: 16 rows x 16x8 f16

  const _Float16* Kbase = Kb + (size_t)(b * N_) * C_ + h * CH_;
  const _Float16* Vbase = Vt + (size_t)((b * H_ + h) * CH_) * N_;

  // prologue: prefetch kt=0 into registers
  f16x8 kr[4], vr[4];
  #pragma unroll
  for (int p = 0; p < 4; p++) {
    kr[p] = *(const f16x8*)(Kbase + (size_t)(p * 32 + srow) * C_ + scol * 8);
    vr[p] = *(const f16x8*)(Vbase + (size_t)(p * 16 + vrow) * N_ + vcol * 8);
  }

  for (int kt = 0; kt < 8; kt++) {
    __syncthreads();
    #pragma unroll
    for (int p = 0; p < 4; p++) {
      int r = p * 32 + srow;
      *(f16x8*)(ldsK + ((r * 128 + scol * 16) ^ ((r & 7) << 4))) = kr[p];
      int rv = p * 16 + vrow;
      *(f16x8*)(ldsV + ((rv * 256 + vcol * 16) ^ ((rv & 7) << 4))) = vr[p];
    }
    __syncthreads();
    // prefetch kt+1 (latency hides under this iteration's compute)
    if (kt < 7) {
      #pragma unroll
      for (int p = 0; p < 4; p++) {
        kr[p] = *(const f16x8*)(Kbase + (size_t)((kt + 1) * 128 + p * 32 + srow) * C_ + scol * 8);
        vr[p] = *(const f16x8*)(Vbase + (size_t)(p * 16 + vrow) * N_ + (kt + 1) * 128 + vcol * 8);
      }
    }
    // bias loads (independent of LDS): combined bias_pair + bias_mask, float4 per 16-k tile
    f32x4 bias[8];
    {
      const float* bp = bias_pair + ((size_t)h * N_ + q0 + w * 16 + lr) * N_ + kt * 128 + lg * 4;
      const float* bm = bias_mask + b * N_ + kt * 128 + lg * 4;
      #pragma unroll
      for (int ct = 0; ct < 8; ct++)
        bias[ct] = *(const f32x4*)(bp + ct * 16) + *(const f32x4*)(bm + ct * 16);
    }
    // S^T = K Q^T : rows k = ct*16+lg*4+r, col q = lr
    f32x4 s[8];
    #pragma unroll
    for (int ct = 0; ct < 8; ct++) {
      #pragma unroll
      for (int r = 0; r < 4; r++) s[ct][r] = 0.f;
      #pragma unroll
      for (int kh = 0; kh < 2; kh++) {
        int row = ct * 16 + lr;
        f16x8 kf = *(const f16x8*)(ldsK + ((row * 128 + kh * 64 + lg * 16) ^ ((row & 7) << 4)));
        s[ct] = __builtin_amdgcn_mfma_f32_16x16x32_f16(kf, qf[kh], s[ct], 0, 0, 0);
      }
      s[ct] += bias[ct];
    }
    // online softmax: per-lane scalar over 32 regs, then 2 shfls across lg groups
    float mx = s[0][0];
    #pragma unroll
    for (int ct = 0; ct < 8; ct++)
      #pragma unroll
      for (int r = 0; r < 4; r++) mx = fmaxf(mx, s[ct][r]);
    mx = fmaxf(mx, __shfl_xor(mx, 16, 64));
    mx = fmaxf(mx, __shfl_xor(mx, 32, 64));
    float m_new = fmaxf(m_run, mx);
    float sc = __expf(m_run - m_new);
    m_run = m_new;
    float sum = 0.f;
    #pragma unroll
    for (int ct = 0; ct < 8; ct++)
      #pragma unroll
      for (int r = 0; r < 4; r++) {
        float p = __expf(s[ct][r] - m_new);
        s[ct][r] = p;
        sum += p;
      }
    sum += __shfl_xor(sum, 16, 64);
    sum += __shfl_xor(sum, 32, 64);
    l_run = l_run * sc + sum;
    #pragma unroll
    for (int j = 0; j < 4; j++)
      #pragma unroll
      for (int r = 0; r < 4; r++) acc_o[j][r] *= sc;
    // P^T -> per-wave LDS [q][k]: f16x4 (4 consecutive k) per reg-quad
    char* myP = ldsP + w * 4096;
    #pragma unroll
    for (int ct = 0; ct < 8; ct++) {
      f16x4 pk;
      #pragma unroll
      for (int r = 0; r < 4; r++) pk[r] = (_Float16)s[ct][r];
      *(f16x4*)(myP + ((lr * 256 + ct * 32 + lg * 8) ^ ((lr & 7) << 4))) = pk;
    }
    // O^T += V^T P^T : A = V^T (ch rows), B = P^T (q cols)
    #pragma unroll
    for (int ks = 0; ks < 4; ks++) {
      f16x8 pf = *(const f16x8*)(myP + ((lr * 256 + ks * 64 + lg * 16) ^ ((lr & 7) << 4)));
      #pragma unroll
      for (int cc = 0; cc < 4; cc++) {
        int vrr = cc * 16 + lr;
        f16x8 vf = *(const f16x8*)(ldsV + ((vrr * 256 + ks * 64 + lg * 16) ^ ((vrr & 7) << 4)));
        acc_o[cc] = __builtin_amdgcn_mfma_f32_16x16x32_f16(vf, pf, acc_o[cc], 0, 0, 0);
      }
    }
  }

  // epilogue: 1/l, gate, vectorized f16x4 store
  {
    int token = b * N_ + q0 + w * 16 + lr;
    float inv_l = 1.f / l_run;
    #pragma unroll
    for (int cc = 0; cc < 4; cc++) {
      int col = h * CH_ + cc * 16 + lg * 4;
      f16x4 g4 = *(const f16x4*)(Gb + (size_t)token * C_ + col);
      f16x4 o4;
      #pragma unroll
      for (int r = 0; r < 4; r++)
        o4[r] = (_Float16)(acc_o[cc][r] * inv_l * (float)g4[r]);
      *(f16x4*)(Ob + (size_t)token * C_ + col) = o4;
    }
  }
}

// ---------------- Kernel 5: output GEMM + bo ----------------
__global__ __launch_bounds__(256, 2) void out_gemm(
    const _Float16* __restrict__ Ob, const _Float16* __restrict__ WTo,
    const float* __restrict__ bo, float* __restrict__ out) {
  int n0 = blockIdx.x * 128;
  int m0 = blockIdx.y * 128;
  __shared__ __align__(16) char lds[32768];
  char* ldsA = lds;
  char* ldsB = lds + 16384;
  int tid = threadIdx.x;
  int lane = tid & 63, w = tid >> 6;
  int wr = w >> 1, wc = w & 1;
  int lr = lane & 15, lg = lane >> 4;
  f32x4 acc[4][4];
  #pragma unroll
  for (int i = 0; i < 4; i++)
    #pragma unroll
    for (int j = 0; j < 4; j++)
      #pragma unroll
      for (int r = 0; r < 4; r++) acc[i][j][r] = 0.f;
  int srow = tid >> 3, scol = tid & 7;
  for (int k0 = 0; k0 < C_; k0 += 64) {
    __syncthreads();
    #pragma unroll
    for (int p = 0; p < 4; p++) {
      int r = p * 32 + srow;
      *(f16x8*)(ldsA + ((r * 128 + scol * 16) ^ ((r & 7) << 4))) =
          *(const f16x8*)(Ob + (size_t)(m0 + r) * C_ + k0 + scol * 8);
      *(f16x8*)(ldsB + ((r * 128 + scol * 16) ^ ((r & 7) << 4))) =
          *(const f16x8*)(WTo + (size_t)(n0 + r) * C_ + k0 + scol * 8);
    }
    __syncthreads();
    #pragma unroll
    for (int kh = 0; kh < 2; kh++) {
      f16x8 a[4], bfr[4];
      #pragma unroll
      for (int i = 0; i < 4; i++) {
        int row = wr * 64 + i * 16 + lr;
        a[i] = *(const f16x8*)(ldsA + ((row * 128 + kh * 64 + lg * 16) ^ ((row & 7) << 4)));
        int col = wc * 64 + i * 16 + lr;
        bfr[i] = *(const f16x8*)(ldsB + ((col * 128 + kh * 64 + lg * 16) ^ ((col & 7) << 4)));
      }
      #pragma unroll
      for (int i = 0; i < 4; i++)
        #pragma unroll
        for (int j = 0; j < 4; j++)
          acc[i][j] = __builtin_amdgcn_mfma_f32_16x16x32_f16(a[i], bfr[j], acc[i][j], 0, 0, 0);
    }
  }
  #pragma unroll
  for (int i = 0; i < 4; i++) {
    int token = m0 + wr * 64 + i * 16 + lg * 4;
    #pragma unroll
    for (int j = 0; j < 4; j++) {
      int col = n0 + wc * 64 + j * 16 + lr;
      float bb = bo[col];
      #pragma unroll
      for (int r = 0; r < 4; r++)
        out[(size_t)(token + r) * C_ + col] = acc[i][j][r] + bb;
    }
  }
}

extern "C" void kernel_launch(void* const* d_in, const int* in_sizes, int n_in,
                              void* d_out, int out_size, void* d_ws, size_t ws_size,
                              hipStream_t stream) {
  const float* q_x = (const float*)d_in[0];
  const float* kv_x = (const float*)d_in[1];
  const float* bias_mask = (const float*)d_in[2];
  const float* bias_pair = (const float*)d_in[3];
  const float* Wq = (const float*)d_in[4];
  const float* Wk = (const float*)d_in[5];
  const float* Wv = (const float*)d_in[6];
  const float* Wg = (const float*)d_in[7];
  const float* bg = (const float*)d_in[8];
  const float* Wo = (const float*)d_in[9];
  const float* bo = (const float*)d_in[10];
  float* out = (float*)d_out;

  char* ws = (char*)d_ws;
  const size_t MB = 1024 * 1024;
  _Float16* xq16 = (_Float16*)(ws + 0);        // 4 MB
  _Float16* xkv16 = (_Float16*)(ws + 4 * MB);  // 4 MB
  _Float16* WT = (_Float16*)(ws + 8 * MB);     // 2.5 MB (5 x 512 x 512 f16)
  _Float16* Qb = (_Float16*)(ws + 11 * MB);    // 4 MB
  _Float16* Kb = (_Float16*)(ws + 15 * MB);    // 4 MB
  _Float16* Vt = (_Float16*)(ws + 19 * MB);    // 4 MB
  _Float16* Gb = (_Float16*)(ws + 23 * MB);    // 4 MB (f16 gate)
  _Float16* Ob = (_Float16*)(ws + 31 * MB);    // 4 MB

  cvt_f32_f16<<<2048, 256, 0, stream>>>(q_x, kv_x, xq16, xkv16);
  transpose_w<<<dim3(16, 16, 5), 256, 0, stream>>>(Wq, Wk, Wv, Wg, Wo, WT);
  proj_gemm<<<dim3(16, 32), 256, 0, stream>>>(xq16, xkv16, WT, bg, Qb, Kb, Vt, Gb);
  attn<<<512, 256, 0, stream>>>(Qb, Kb, Vt, Gb, bias_mask, bias_pair, Ob);
  out_gemm<<<dim3(4, 32), 256, 0, stream>>>(Ob, WT + 4 * (size_t)C_ * C_, bo, out);
}